// Round 1
// baseline (376.138 us; speedup 1.0000x reference)
//
#include <hip/hip_runtime.h>
#include <hip/hip_bf16.h>

typedef __attribute__((ext_vector_type(8))) short bf16x8;
typedef __attribute__((ext_vector_type(4))) float f32x4;

// Problem constants
#define NB    8      // batches
#define ND1   16     // D1
#define NN    2048   // N (nodes)
#define NF    64     // F_IN = F_OUT
#define GN    1024   // GEMM N-dim = D1*F_OUT
// GEMM per batch: C[2048 x 1024] = adj[2048 x 2048] * support[2048 x 1024]

__device__ static inline ushort f2bf(float f) {
    // round-to-nearest-even fp32 -> bf16 (inputs are finite randoms; no NaN path)
    unsigned int u = __builtin_bit_cast(unsigned int, f);
    unsigned int r = (u + 0x7FFFu + ((u >> 16) & 1u)) >> 16;
    return (ushort)r;
}

__device__ static inline void gload_lds16(const void* g, void* l) {
    __builtin_amdgcn_global_load_lds(
        (const __attribute__((address_space(1))) void*)g,
        (__attribute__((address_space(3))) void*)l, 16, 0, 0);
}

// ---------------------------------------------------------------------------
// Kernel 1: adj fp32 -> bf16 (elementwise)
// ---------------------------------------------------------------------------
__global__ __launch_bounds__(256) void conv_adj_kernel(
    const float* __restrict__ adj, ushort* __restrict__ adjb, int n4)
{
    int idx = blockIdx.x * blockDim.x + threadIdx.x;
    int stride = gridDim.x * blockDim.x;
    const float4* a4 = (const float4*)adj;
    ushort4* o4 = (ushort4*)adjb;
    for (int i = idx; i < n4; i += stride) {
        float4 v = a4[i];
        ushort4 r;
        r.x = f2bf(v.x); r.y = f2bf(v.y); r.z = f2bf(v.z); r.w = f2bf(v.w);
        o4[i] = r;
    }
}

// ---------------------------------------------------------------------------
// Kernel 2: support_T[b][i*64+g][m] (bf16) = sum_f x[b,i,m,f] * W[f,g]
// One block per (b, i, 64-row m-slab). fp32 compute, transpose via LDS.
// ---------------------------------------------------------------------------
__global__ __launch_bounds__(256) void support_kernel(
    const float* __restrict__ x, const float* __restrict__ w,
    ushort* __restrict__ sT)
{
    __shared__ __align__(16) float Ws[64 * 64];
    __shared__ __align__(16) float xs[64 * 65];   // +1 pad: conflict-free col reads
    __shared__ __align__(16) ushort tr[64 * 72];  // [g][m] transposed staging

    int t = threadIdx.x;
    int bid = blockIdx.x;
    int b  = bid >> 9;        // 512 blocks per batch (16 i * 32 mb)
    int r  = bid & 511;
    int i  = r >> 5;
    int mb = r & 31;

    // Load W[64][64] and x-slab[64 m][64 f] (both fully coalesced float4)
    const float4* w4 = (const float4*)w;
    const float4* x4 = (const float4*)(x + (((size_t)(b * ND1 + i)) * NN + mb * 64) * NF);
#pragma unroll
    for (int j = 0; j < 4; ++j) {
        float4 wv = w4[j * 256 + t];
        int fl = j * 1024 + t * 4;
        Ws[fl + 0] = wv.x; Ws[fl + 1] = wv.y; Ws[fl + 2] = wv.z; Ws[fl + 3] = wv.w;
        float4 xv = x4[j * 256 + t];
        int ml = fl >> 6, f = fl & 63;
        float* xr = &xs[ml * 65 + f];
        xr[0] = xv.x; xr[1] = xv.y; xr[2] = xv.z; xr[3] = xv.w;
    }
    __syncthreads();

    // Each thread: one m-row (ml = lane), 16 g-values (per-wave g0)
    int ml = t & 63;
    int g0 = (t >> 6) * 16;
    f32x4 acc4[4] = {0.f, 0.f, 0.f, 0.f};
    for (int f = 0; f < 64; ++f) {
        float xv = xs[ml * 65 + f];                       // 2-way bank alias: free
        const f32x4* wp = (const f32x4*)&Ws[f * 64 + g0]; // wave-broadcast reads
#pragma unroll
        for (int q = 0; q < 4; ++q) acc4[q] += xv * wp[q];
    }
#pragma unroll
    for (int j = 0; j < 16; ++j)
        tr[(g0 + j) * 72 + ml] = f2bf(acc4[j >> 2][j & 3]);
    __syncthreads();

    // Write out: row = b*1024 + i*64 + g, cols mb*64 .. +64 (contiguous bf16)
    int g = t >> 2, part = t & 3;
    const uint4* src = (const uint4*)&tr[g * 72 + part * 16];
    uint4* dst = (uint4*)(sT + ((size_t)(b * GN + i * 64 + g)) * NN + mb * 64 + part * 16);
    dst[0] = src[0];
    dst[1] = src[1];
}

// ---------------------------------------------------------------------------
// Kernel 3: batched GEMM  out[b][i][n][g] = sum_m adj[b][n][m] * support[b,i,m,g]
// m97 structure: 128x128 tile, BK=64, 4 waves, 16x16x32 bf16 MFMA.
// PRECONV: A staged from preconverted bf16 via global_load_lds;
// else A reg-staged from fp32 with in-register conversion.
// ---------------------------------------------------------------------------
template <bool PRECONV>
__global__ __launch_bounds__(256) void gcn_gemm_kernel(
    const ushort* __restrict__ adjb,  // bf16 adj (PRECONV)
    const float* __restrict__ adjf,   // fp32 adj (!PRECONV)
    const ushort* __restrict__ sT,    // bf16 support_T [b][1024][2048]
    float* __restrict__ out)          // fp32 [b][16][2048][64]
{
    __shared__ __align__(16) ushort lA[128 * 64];
    __shared__ __align__(16) ushort lB[128 * 64];

    int t = threadIdx.x;

    // XCD-aware swizzle: 1024 blocks, 8 XCDs, contiguous 128-block chunks
    int bid0 = blockIdx.x;
    int bid = (bid0 & 7) * 128 + (bid0 >> 3);

    int b  = bid >> 7;        // 128 tiles per batch
    int rr = bid & 127;
    int mt = rr >> 3;         // 16 M-tiles (n)
    int nt = rr & 7;          // 8 N-tiles (ig)
    int n0 = mt * 128;
    int c0 = nt * 128;

    const ushort* Ab = adjb + (size_t)b * NN * NN;
    const float*  Af = adjf + (size_t)b * NN * NN;
    const ushort* Bb = sT + (size_t)b * GN * NN;

    int lane = t & 63, wv = t >> 6;
    int wr = (wv >> 1) * 64, wc = (wv & 1) * 64;

    f32x4 acc[4][4];
#pragma unroll
    for (int a = 0; a < 4; ++a)
#pragma unroll
        for (int c = 0; c < 4; ++c) acc[a][c] = (f32x4){0.f, 0.f, 0.f, 0.f};

    int sRow = t >> 3;        // 0..31
    int sCol = (t & 7) * 8;   // bf16 elems, 16B granules

    for (int k0 = 0; k0 < NN; k0 += 64) {
        // ---- stage A tile [128 n][64 k] ----
        if (PRECONV) {
#pragma unroll
            for (int i = 0; i < 4; ++i)
                gload_lds16(Ab + (size_t)(n0 + i * 32 + sRow) * NN + k0 + sCol,
                            &lA[(i * 32 + sRow) * 64 + sCol]);
        } else {
#pragma unroll
            for (int i = 0; i < 4; ++i) {
                const float* src = Af + (size_t)(n0 + i * 32 + sRow) * NN + k0 + sCol;
                float4 v0 = *(const float4*)src;
                float4 v1 = *(const float4*)(src + 4);
                union { bf16x8 v; ushort u[8]; } p;
                p.u[0] = f2bf(v0.x); p.u[1] = f2bf(v0.y);
                p.u[2] = f2bf(v0.z); p.u[3] = f2bf(v0.w);
                p.u[4] = f2bf(v1.x); p.u[5] = f2bf(v1.y);
                p.u[6] = f2bf(v1.z); p.u[7] = f2bf(v1.w);
                *(bf16x8*)&lA[(i * 32 + sRow) * 64 + sCol] = p.v;
            }
        }
        // ---- stage B tile [128 ig][64 k] ----
#pragma unroll
        for (int i = 0; i < 4; ++i)
            gload_lds16(Bb + (size_t)(c0 + i * 32 + sRow) * NN + k0 + sCol,
                        &lB[(i * 32 + sRow) * 64 + sCol]);

        __syncthreads();

#pragma unroll
        for (int kk = 0; kk < 2; ++kk) {
            bf16x8 af[4], bfr[4];
#pragma unroll
            for (int a = 0; a < 4; ++a)
                af[a] = *(const bf16x8*)&lA[(wr + a * 16 + (lane & 15)) * 64 + kk * 32 + (lane >> 4) * 8];
#pragma unroll
            for (int c = 0; c < 4; ++c)
                bfr[c] = *(const bf16x8*)&lB[(wc + c * 16 + (lane & 15)) * 64 + kk * 32 + (lane >> 4) * 8];
#pragma unroll
            for (int a = 0; a < 4; ++a)
#pragma unroll
                for (int c = 0; c < 4; ++c)
                    acc[a][c] = __builtin_amdgcn_mfma_f32_16x16x32_bf16(af[a], bfr[c], acc[a][c], 0, 0, 0);
        }
        __syncthreads();
    }

    // ---- epilogue: C[row=n][col=ig] -> out[b][ig>>6][n][ig&63] ----
#pragma unroll
    for (int a = 0; a < 4; ++a) {
        int row0 = n0 + wr + a * 16 + (lane >> 4) * 4;
#pragma unroll
        for (int c = 0; c < 4; ++c) {
            int col = c0 + wc + c * 16 + (lane & 15);
            int ii = col >> 6, g = col & 63;
            float* op = out + (((size_t)(b * ND1 + ii)) * NN + row0) * NF + g;
#pragma unroll
            for (int e = 0; e < 4; ++e)
                op[e * NF] = acc[a][c][e];
        }
    }
}

// ---------------------------------------------------------------------------
extern "C" void kernel_launch(void* const* d_in, const int* in_sizes, int n_in,
                              void* d_out, int out_size, void* d_ws, size_t ws_size,
                              hipStream_t stream) {
    const float* x   = (const float*)d_in[0];  // [8,16,2048,64]
    const float* adj = (const float*)d_in[1];  // [8,2048,2048]
    const float* w   = (const float*)d_in[2];  // [64,64]
    float* out = (float*)d_out;

    ushort* sT   = (ushort*)d_ws;                          // 33,554,432 B
    ushort* adjb = (ushort*)((char*)d_ws + 33554432);      // 67,108,864 B
    bool preconv = ws_size >= (size_t)100663296;

    // support_T
    support_kernel<<<dim3(NB * ND1 * (NN / 64)), dim3(256), 0, stream>>>(x, w, sT);

    if (preconv) {
        conv_adj_kernel<<<dim3(2048), dim3(256), 0, stream>>>(adj, adjb, NB * NN * NN / 4);
        gcn_gemm_kernel<true><<<dim3(NB * 16 * 8), dim3(256), 0, stream>>>(adjb, nullptr, sT, out);
    } else {
        gcn_gemm_kernel<false><<<dim3(NB * 16 * 8), dim3(256), 0, stream>>>(nullptr, adj, sT, out);
    }
}

// Round 2
// 341.024 us; speedup vs baseline: 1.1030x; 1.1030x over previous
//
#include <hip/hip_runtime.h>
#include <hip/hip_bf16.h>

typedef __attribute__((ext_vector_type(8))) short bf16x8;
typedef __attribute__((ext_vector_type(4))) float f32x4;

// Problem constants
#define NB    8      // batches
#define ND1   16     // D1
#define NN    2048   // N (nodes)
#define NF    64     // F_IN = F_OUT
#define GN    1024   // GEMM N-dim = D1*F_OUT
// GEMM per batch: C[2048 x 1024] = adj[2048 x 2048] * support_T[1024 x 2048]^T

__device__ static inline ushort f2bf(float f) {
    unsigned int u = __builtin_bit_cast(unsigned int, f);
    unsigned int r = (u + 0x7FFFu + ((u >> 16) & 1u)) >> 16;
    return (ushort)r;
}

__device__ static inline void gload_lds16(const void* g, void* l) {
    __builtin_amdgcn_global_load_lds(
        (const __attribute__((address_space(1))) void*)g,
        (__attribute__((address_space(3))) void*)l, 16, 0, 0);
}

// ---------------------------------------------------------------------------
// Kernel 1: adj fp32 -> bf16 (elementwise)
// ---------------------------------------------------------------------------
__global__ __launch_bounds__(256) void conv_adj_kernel(
    const float* __restrict__ adj, ushort* __restrict__ adjb, int n4)
{
    int idx = blockIdx.x * blockDim.x + threadIdx.x;
    int stride = gridDim.x * blockDim.x;
    const float4* a4 = (const float4*)adj;
    ushort4* o4 = (ushort4*)adjb;
    for (int i = idx; i < n4; i += stride) {
        float4 v = a4[i];
        ushort4 r;
        r.x = f2bf(v.x); r.y = f2bf(v.y); r.z = f2bf(v.z); r.w = f2bf(v.w);
        o4[i] = r;
    }
}

// ---------------------------------------------------------------------------
// Kernel 2: support_T[b][i*64+g][m] (bf16) = sum_f x[b,i,m,f] * W[f,g]
// ---------------------------------------------------------------------------
__global__ __launch_bounds__(256) void support_kernel(
    const float* __restrict__ x, const float* __restrict__ w,
    ushort* __restrict__ sT)
{
    __shared__ __align__(16) float Ws[64 * 64];
    __shared__ __align__(16) float xs[64 * 65];
    __shared__ __align__(16) ushort tr[64 * 72];

    int t = threadIdx.x;
    int bid = blockIdx.x;
    int b  = bid >> 9;
    int r  = bid & 511;
    int i  = r >> 5;
    int mb = r & 31;

    const float4* w4 = (const float4*)w;
    const float4* x4 = (const float4*)(x + (((size_t)(b * ND1 + i)) * NN + mb * 64) * NF);
#pragma unroll
    for (int j = 0; j < 4; ++j) {
        float4 wv = w4[j * 256 + t];
        int fl = j * 1024 + t * 4;
        Ws[fl + 0] = wv.x; Ws[fl + 1] = wv.y; Ws[fl + 2] = wv.z; Ws[fl + 3] = wv.w;
        float4 xv = x4[j * 256 + t];
        int ml = fl >> 6, f = fl & 63;
        float* xr = &xs[ml * 65 + f];
        xr[0] = xv.x; xr[1] = xv.y; xr[2] = xv.z; xr[3] = xv.w;
    }
    __syncthreads();

    int ml = t & 63;
    int g0 = (t >> 6) * 16;
    f32x4 acc4[4] = {0.f, 0.f, 0.f, 0.f};
    for (int f = 0; f < 64; ++f) {
        float xv = xs[ml * 65 + f];
        const f32x4* wp = (const f32x4*)&Ws[f * 64 + g0];
#pragma unroll
        for (int q = 0; q < 4; ++q) acc4[q] += xv * wp[q];
    }
#pragma unroll
    for (int j = 0; j < 16; ++j)
        tr[(g0 + j) * 72 + ml] = f2bf(acc4[j >> 2][j & 3]);
    __syncthreads();

    int g = t >> 2, part = t & 3;
    const uint4* src = (const uint4*)&tr[g * 72 + part * 16];
    uint4* dst = (uint4*)(sT + ((size_t)(b * GN + i * 64 + g)) * NN + mb * 64 + part * 16);
    dst[0] = src[0];
    dst[1] = src[1];
}

// ---------------------------------------------------------------------------
// Kernel 3: phased 256x256-tile GEMM, BK=32, 3 LDS buffers, counted vmcnt.
//   out[b][i][n][g] = sum_m adj[b][n][m] * support[b,i,m,g]
// 8 waves (2M x 4N), per-wave C = 128x64 (8x4 frags of 16x16).
// LDS layout per op-tile (16 KB): 16 stripes (16 rows each) x 64 granules
// (16B); granule (r,c) at stripe_base + (c*16 + r)*16B  -> conflict-free
// ds_read_b128 fragment loads. global_load_lds writes linearly; the per-lane
// GLOBAL source is pre-permuted to match (rule 21).
// ---------------------------------------------------------------------------
__global__ __launch_bounds__(512, 2) void gemm8_kernel(
    const ushort* __restrict__ adjb,  // bf16 adj [b][2048][2048]
    const ushort* __restrict__ sT,    // bf16 support_T [b][1024][2048]
    float* __restrict__ out)          // fp32 [b][16][2048][64]
{
    __shared__ __align__(16) ushort lds[3 * 16384];  // 3 x (A 16KB + B 16KB)

    const int t    = threadIdx.x;
    const int lane = t & 63;
    const int w    = t >> 6;      // wave 0..7
    const int wm   = w >> 2;      // 0..1  (M half)
    const int wn   = w & 3;       // 0..3  (N quarter)

    // XCD-bijective tile map: 256 blocks, XCD k owns batch k entirely.
    int bid  = blockIdx.x;
    int tile = (bid & 7) * 32 + (bid >> 3);
    int b    = tile >> 5;
    int r    = tile & 31;
    int n0   = (r >> 2) * 256;    // 8 M-tiles
    int c0   = (r & 3) * 256;     // 4 N-tiles

    const ushort* Ab = adjb + (size_t)b * NN * NN + (size_t)n0 * NN;
    const ushort* Bb = sT   + (size_t)b * GN * NN + (size_t)c0 * NN;

    // staging: thread stages granule (r=lane&15, c=lane>>4) of stripe j*8+w
    const int rS  = lane & 15;
    const int cgS = lane >> 4;
    // fragment-read offset within a stripe (ushort units)
    const int fq  = ((lane >> 4) * 16 + (lane & 15)) * 8;

    f32x4 acc[8][4];
#pragma unroll
    for (int a = 0; a < 8; ++a)
#pragma unroll
        for (int c = 0; c < 4; ++c) acc[a][c] = (f32x4){0.f, 0.f, 0.f, 0.f};

    auto stageA = [&](int kt, int q) {
#pragma unroll
        for (int j = 0; j < 2; ++j) {
            int stripe = j * 8 + w;
            gload_lds16(Ab + (size_t)(stripe * 16 + rS) * NN + kt * 32 + cgS * 8,
                        &lds[q * 16384 + j * 4096 + w * 512 + lane * 8]);
        }
    };
    auto stageB = [&](int kt, int q) {
#pragma unroll
        for (int j = 0; j < 2; ++j) {
            int stripe = j * 8 + w;
            gload_lds16(Bb + (size_t)(stripe * 16 + rS) * NN + kt * 32 + cgS * 8,
                        &lds[q * 16384 + 8192 + j * 4096 + w * 512 + lane * 8]);
        }
    };

    // prologue: tiles 0 and 1 into buffers 0 and 1 (4 loads each per thread)
    stageA(0, 0); stageB(0, 0);
    stageA(1, 1); stageB(1, 1);

    int q = 0, qn = 2;
    for (int kt = 0; kt < 64; ++kt) {
        // wait tile-kt's 4 loads landed (tiles kt+1 may stay in flight)
        if (kt < 63) asm volatile("s_waitcnt vmcnt(4)" ::: "memory");
        else         asm volatile("s_waitcnt vmcnt(0)" ::: "memory");
        asm volatile("s_barrier" ::: "memory");

        const ushort* La = &lds[q * 16384];
        const ushort* Lb = &lds[q * 16384 + 8192];

        // ---- phase 0: a0-3 x c0-3 ----
        bf16x8 af[4], bfr[4];
#pragma unroll
        for (int a = 0; a < 4; ++a)
            af[a] = *(const bf16x8*)&La[(wm * 8 + a) * 512 + fq];
#pragma unroll
        for (int c = 0; c < 4; ++c)
            bfr[c] = *(const bf16x8*)&Lb[(wn * 4 + c) * 512 + fq];
        if (kt < 62) stageA(kt + 2, qn);
        asm volatile("s_barrier" ::: "memory");
        __builtin_amdgcn_s_setprio(1);
#pragma unroll
        for (int a = 0; a < 4; ++a)
#pragma unroll
            for (int c = 0; c < 4; ++c)
                acc[a][c] = __builtin_amdgcn_mfma_f32_16x16x32_bf16(af[a], bfr[c], acc[a][c], 0, 0, 0);
        __builtin_amdgcn_s_setprio(0);

        // ---- phase 1: a4-7 x c0-3 (B frags reused in registers) ----
#pragma unroll
        for (int a = 0; a < 4; ++a)
            af[a] = *(const bf16x8*)&La[(wm * 8 + 4 + a) * 512 + fq];
        if (kt < 62) stageB(kt + 2, qn);
        asm volatile("s_barrier" ::: "memory");
        __builtin_amdgcn_s_setprio(1);
#pragma unroll
        for (int a = 0; a < 4; ++a)
#pragma unroll
            for (int c = 0; c < 4; ++c)
                acc[4 + a][c] = __builtin_amdgcn_mfma_f32_16x16x32_bf16(af[a], bfr[c], acc[4 + a][c], 0, 0, 0);
        __builtin_amdgcn_s_setprio(0);

        q  = (q  == 2) ? 0 : q  + 1;
        qn = (qn == 2) ? 0 : qn + 1;
    }

    // ---- epilogue ----
#pragma unroll
    for (int a = 0; a < 8; ++a) {
        int row0 = n0 + wm * 128 + a * 16 + (lane >> 4) * 4;
#pragma unroll
        for (int c = 0; c < 4; ++c) {
            int col = c0 + wn * 64 + c * 16 + (lane & 15);
            int ii = col >> 6, g = col & 63;
            float* op = out + (((size_t)(b * ND1 + ii)) * NN + row0) * NF + g;
#pragma unroll
            for (int e = 0; e < 4; ++e)
                op[e * NF] = acc[a][c][e];
        }
    }
}

// ---------------------------------------------------------------------------
// Fallback GEMM (128^2, reg-staged fp32->bf16 convert) if ws too small
// ---------------------------------------------------------------------------
__global__ __launch_bounds__(256) void gcn_gemm_fb_kernel(
    const float* __restrict__ adjf, const ushort* __restrict__ sT,
    float* __restrict__ out)
{
    __shared__ __align__(16) ushort lA[128 * 64];
    __shared__ __align__(16) ushort lB[128 * 64];

    int t = threadIdx.x;
    int bid0 = blockIdx.x;
    int bid = (bid0 & 7) * 128 + (bid0 >> 3);
    int b  = bid >> 7;
    int rr = bid & 127;
    int n0 = (rr >> 3) * 128;
    int c0 = (rr & 7) * 128;

    const float*  Af = adjf + (size_t)b * NN * NN;
    const ushort* Bb = sT + (size_t)b * GN * NN;

    int lane = t & 63, wv = t >> 6;
    int wr = (wv >> 1) * 64, wc = (wv & 1) * 64;

    f32x4 acc[4][4];
#pragma unroll
    for (int a = 0; a < 4; ++a)
#pragma unroll
        for (int c = 0; c < 4; ++c) acc[a][c] = (f32x4){0.f, 0.f, 0.f, 0.f};

    int sRow = t >> 3;
    int sCol = (t & 7) * 8;

    for (int k0 = 0; k0 < NN; k0 += 64) {
#pragma unroll
        for (int i = 0; i < 4; ++i) {
            const float* src = Af + (size_t)(n0 + i * 32 + sRow) * NN + k0 + sCol;
            float4 v0 = *(const float4*)src;
            float4 v1 = *(const float4*)(src + 4);
            union { bf16x8 v; ushort u[8]; } p;
            p.u[0] = f2bf(v0.x); p.u[1] = f2bf(v0.y);
            p.u[2] = f2bf(v0.z); p.u[3] = f2bf(v0.w);
            p.u[4] = f2bf(v1.x); p.u[5] = f2bf(v1.y);
            p.u[6] = f2bf(v1.z); p.u[7] = f2bf(v1.w);
            *(bf16x8*)&lA[(i * 32 + sRow) * 64 + sCol] = p.v;
        }
#pragma unroll
        for (int i = 0; i < 4; ++i)
            gload_lds16(Bb + (size_t)(c0 + i * 32 + sRow) * NN + k0 + sCol,
                        &lB[(i * 32 + sRow) * 64 + sCol]);
        __syncthreads();
#pragma unroll
        for (int kk = 0; kk < 2; ++kk) {
            bf16x8 af[4], bfr[4];
#pragma unroll
            for (int a = 0; a < 4; ++a)
                af[a] = *(const bf16x8*)&lA[(wr + a * 16 + (lane & 15)) * 64 + kk * 32 + (lane >> 4) * 8];
#pragma unroll
            for (int c = 0; c < 4; ++c)
                bfr[c] = *(const bf16x8*)&lB[(wc + c * 16 + (lane & 15)) * 64 + kk * 32 + (lane >> 4) * 8];
#pragma unroll
            for (int a = 0; a < 4; ++a)
#pragma unroll
                for (int c = 0; c < 4; ++c)
                    acc[a][c] = __builtin_amdgcn_mfma_f32_16x16x32_bf16(af[a], bfr[c], acc[a][c], 0, 0, 0);
        }
        __syncthreads();
    }
#pragma unroll
    for (int a = 0; a < 4; ++a) {
        int row0 = n0 + wr + a * 16 + (lane >> 4) * 4;
#pragma unroll
        for (int c = 0; c < 4; ++c) {
            int col = c0 + wc + c * 16 + (lane & 15);
            int ii = col >> 6, g = col & 63;
            float* op = out + (((size_t)(b * ND1 + ii)) * NN + row0) * NF + g;
#pragma unroll
            for (int e = 0; e < 4; ++e)
                op[e * NF] = acc[a][c][e];
        }
    }
}

// ---------------------------------------------------------------------------
extern "C" void kernel_launch(void* const* d_in, const int* in_sizes, int n_in,
                              void* d_out, int out_size, void* d_ws, size_t ws_size,
                              hipStream_t stream) {
    const float* x   = (const float*)d_in[0];  // [8,16,2048,64]
    const float* adj = (const float*)d_in[1];  // [8,2048,2048]
    const float* w   = (const float*)d_in[2];  // [64,64]
    float* out = (float*)d_out;

    ushort* sT   = (ushort*)d_ws;                          // 33,554,432 B
    ushort* adjb = (ushort*)((char*)d_ws + 33554432);      // 67,108,864 B
    bool preconv = ws_size >= (size_t)100663296;

    support_kernel<<<dim3(NB * ND1 * (NN / 64)), dim3(256), 0, stream>>>(x, w, sT);

    if (preconv) {
        conv_adj_kernel<<<dim3(2048), dim3(256), 0, stream>>>(adj, adjb, NB * NN * NN / 4);
        gemm8_kernel<<<dim3(256), dim3(512), 0, stream>>>(adjb, sT, out);
    } else {
        gcn_gemm_fb_kernel<<<dim3(NB * 16 * 8), dim3(256), 0, stream>>>(adj, sT, out);
    }
}